// Round 6
// baseline (137.117 us; speedup 1.0000x reference)
//
#include <hip/hip_runtime.h>
#include <hip/hip_bf16.h>
#include <math.h>

#define BATCH 16
#define NPTS 1024
#define DIM 64
#define EPSF 0.1f
#define INV_EPS 10.0f
#define MAX_ITER 100
#define THRESHF 0.1f
#define LSTRIDE 72  // shorts; 64+8 pad keeps b128 LDS reads conflict-cheap

typedef _Float16 h8 __attribute__((ext_vector_type(8)));
typedef _Float16 half2v __attribute__((ext_vector_type(2)));
typedef short short8v __attribute__((ext_vector_type(8)));
typedef float float4v __attribute__((ext_vector_type(4)));

// extract packed half pair P (template => parse-time constant indices)
template <int P>
__device__ __forceinline__ half2v h2get(h8 v) {
  return __builtin_shufflevector(v, v, 2 * P, 2 * P + 1);
}

#define ATOMIC_ST(p, v) \
  __hip_atomic_store((p), (v), __ATOMIC_RELAXED, __HIP_MEMORY_SCOPE_AGENT)
#define ATOMIC_LD(p) \
  __hip_atomic_load((p), __ATOMIC_RELAXED, __HIP_MEMORY_SCOPE_AGENT)

__device__ inline float waveSum(float x) {
#pragma unroll
  for (int off = 32; off; off >>= 1) x += __shfl_xor(x, off, 64);
  return x;
}
__device__ inline float waveMax(float x) {
#pragma unroll
  for (int off = 32; off; off >>= 1) x = fmaxf(x, __shfl_xor(x, off, 64));
  return x;
}
__device__ inline long long packTag(int tag, float v) {
  return ((long long)tag << 32) | (long long)__float_as_uint(v);
}
__device__ inline long long pollTag(long long* p, int tag) {
  long long w;
  do { w = ATOMIC_LD(p); } while ((int)(w >> 32) < tag);
  return w;
}

// ---- Phase A (per slab): u update + fp16 column partials ----
// Same math as round 5 (dot2 f32-acc row dots; pk_fma x1024-scaled partials).
#define DOT8(P, KAr, KBr)                                                   \
  d0 = __builtin_amdgcn_fdot2(h2get<P>(KAr), h2get<P>(wh0), d0, false);     \
  d1 = __builtin_amdgcn_fdot2(h2get<P>(KBr), h2get<P>(wh1), d1, false);
#define PKF(P, KAr, KBr)                                                    \
  c0[P] = h2get<P>(KAr) * ai2 + c0[P];                                      \
  c1[P] = h2get<P>(KBr) * ai2 + c1[P];
#define PHASEA_ROW(KAr, KBr, EUr)                                           \
  {                                                                         \
    float d0 = 0.f, d1 = 0.f;                                               \
    DOT8(0, KAr, KBr) DOT8(1, KAr, KBr) DOT8(2, KAr, KBr) DOT8(3, KAr, KBr) \
    float dot = waveSum(d0 + d1);                                           \
    float sp = (EUr) * dot + 1e-6f;                                         \
    float lg = __logf(sp);                                                  \
    delta += fabsf(EPSF * (log_mu - lg)); /* == |u_new - u_old| */          \
    float ai = mu_c * (EUr) * __builtin_amdgcn_rcpf(sp);                    \
    (EUr) = ai;                                                             \
    _Float16 aih = (_Float16)(ai * 1024.0f);                                \
    half2v ai2 = {aih, aih};                                                \
    PKF(0, KAr, KBr) PKF(1, KAr, KBr) PKF(2, KAr, KBr) PKF(3, KAr, KBr)     \
  }
#define PHASEA(WH, KAa, KBa, EUa, CP, DERR)                                 \
  {                                                                         \
    h8 wh0 = *(const h8*)&WH[8 * lane];                                     \
    h8 wh1 = *(const h8*)&WH[512 + 8 * lane];                               \
    half2v c0[4], c1[4];                                                    \
    c0[0] = c0[1] = c0[2] = c0[3] = half2v{(_Float16)0.f, (_Float16)0.f};   \
    c1[0] = c1[1] = c1[2] = c1[3] = half2v{(_Float16)0.f, (_Float16)0.f};   \
    float delta = 0.f;                                                      \
    PHASEA_ROW(KAa[0], KBa[0], EUa[0])                                      \
    PHASEA_ROW(KAa[1], KBa[1], EUa[1])                                      \
    PHASEA_ROW(KAa[2], KBa[2], EUa[2])                                      \
    PHASEA_ROW(KAa[3], KBa[3], EUa[3])                                      \
    if (lane == 0) DERR[wave] = delta;                                      \
    float4* cp = (float4*)&CP[wave][0];                                     \
    cp[2 * lane] = make_float4((float)c0[0][0], (float)c0[0][1],            \
                               (float)c0[1][0], (float)c0[1][1]);           \
    cp[2 * lane + 1] = make_float4((float)c0[2][0], (float)c0[2][1],        \
                                   (float)c0[3][0], (float)c0[3][1]);       \
    cp[128 + 2 * lane] = make_float4((float)c1[0][0], (float)c1[0][1],      \
                                     (float)c1[1][0], (float)c1[1][1]);     \
    cp[128 + 2 * lane + 1] = make_float4((float)c1[2][0], (float)c1[2][1],  \
                                         (float)c1[3][0], (float)c1[3][1]); \
  }

// Round-6: two-slab interleave. 256 blocks x 512 threads, 1 block/CU.
// Block owns slab A = (batch bA=blk&7, rows [s*32,+32)) and slab B =
// (batch bB=bA+8, same rows), s=blk>>3 in [0,32). 32 writer-slabs per batch.
// Per iteration the two slabs' exchanges are software-pipelined so each
// slab's atomic-drain / flag RT / cs flight hides under the OTHER slab's
// compute or poll. Exchange protocol per batch = round-2 (best measured):
// staggered f32 atomicAdd into colsum[3] triple-buffer, 64-bit flags
// tag<<32|delta (fA for slab A, fB for slab B, both indexed [bA][32] by the
// pair), lag-1 errB global early-stop. Poison-compat (0xAA): flag tags
// signed (poison<1), errB "<0" sentinel, costPart +1.0 bias "<0.5"
// sentinel, colsum zeroed in prologue. Cross-block via relaxed agent-scope
// ops (L3); ordering = __syncthreads vmcnt drain + monotonic tags.
__global__ __launch_bounds__(512, 2) void sinkhorn_fused(
    const float* __restrict__ x, const float* __restrict__ y,
    __hip_bfloat16* __restrict__ syh,  // [BATCH*NPTS*DIM] bf16
    float* __restrict__ y2,            // [BATCH*NPTS]
    float* __restrict__ colsum,        // [3][BATCH][NPTS] (scaled x1024)
    long long* __restrict__ fA,        // [8][32]: tag<<32 | deltaA bits
    long long* __restrict__ fB,        // [8][32]: tag<<32 | deltaB bits
    float* __restrict__ errB,          // [MAX_ITER][BATCH], sentinel <0
    float* __restrict__ costPart,      // [256], sentinel <0.5
    float* __restrict__ out) {
  __shared__ __attribute__((aligned(16))) short xs[64 * LSTRIDE];  // A:0-31 B:32-63
  __shared__ __attribute__((aligned(16))) short ys[2][64 * LSTRIDE];
  __shared__ __attribute__((aligned(16))) short os[2][32 * LSTRIDE];
  __shared__ __attribute__((aligned(16))) float wLA[NPTS];
  __shared__ __attribute__((aligned(16))) float wLB[NPTS];
  __shared__ __attribute__((aligned(16))) _Float16 whA[NPTS];
  __shared__ __attribute__((aligned(16))) _Float16 whB[NPTS];
  __shared__ __attribute__((aligned(16))) float cpA[8][NPTS];
  __shared__ __attribute__((aligned(16))) float cpB[8][NPTS];
  __shared__ float x2L[64];
  __shared__ float derrA[8], derrB[8];
  __shared__ float errbL[BATCH];
  const int t = threadIdx.x;
  const int blk = blockIdx.x;
  const int wave = t >> 6, lane = t & 63;
  const int bA = blk & 7, bB = bA + 8;
  const int s = blk >> 3;  // slot 0..31
  const float log_mu = logf(1.0f / 1024.0f + 1e-8f);
  const float mu_c = 1.0f / 1024.0f + 1e-8f;  // exp(log_mu)

  // ---- Phase 0: softmax, 4 rows/wave/slab. x->LDS; y->global via L3. ----
#pragma unroll
  for (int sl = 0; sl < 2; sl++) {
    int b = sl ? bB : bA;
#pragma unroll
    for (int rr = 0; rr < 4; rr++) {
      int rl = wave * 4 + rr;  // 0..31 slab row
      int gr = b * NPTS + s * 32 + rl;
      float xv = x[(size_t)gr * DIM + lane];
      float mx = waveMax(xv);
      float ex = __expf(xv - mx);
      float sx = waveSum(ex);
      float px = ex / sx;
      __hip_bfloat16 hbx = (__hip_bfloat16)px;
      xs[(sl * 32 + rl) * LSTRIDE + lane] = *(const short*)&hbx;
      float sqx = waveSum(px * px);
      if (lane == 0) x2L[sl * 32 + rl] = sqx;
      float yv = y[(size_t)gr * DIM + lane];
      float my = waveMax(yv);
      float ey = __expf(yv - my);
      float sy = waveSum(ey);
      float py = ey / sy;
      __hip_bfloat16 hby = (__hip_bfloat16)py;
      unsigned bits = *(const unsigned short*)&hby;
      unsigned nb = __shfl_down(bits, 1);
      if ((lane & 1) == 0)
        ATOMIC_ST((unsigned*)((unsigned short*)syh + (size_t)gr * DIM + lane),
                  bits | (nb << 16));
      float sqy = waveSum(py * py);
      if (lane == 0) ATOMIC_ST(&y2[gr], sqy);
    }
  }
  // zero own colsum slices: 3 bufs x 2 batches x 32 cols
  if (t < 192) {
    int buf = t >> 6, r = t & 63, sl = r >> 5, c = r & 31;
    int b = sl ? bB : bA;
    ATOMIC_ST(&colsum[((size_t)buf * BATCH + b) * NPTS + s * 32 + c], 0.f);
  }
  __syncthreads();  // vmcnt drain: y/y2/zero stores at L3
  if (t == 0) ATOMIC_ST(&fA[bA * 32 + s], (long long)1 << 32);
  if (t < 32) {
    while ((int)(ATOMIC_LD(&fA[bA * 32 + t]) >> 32) < 1) {}
  }
  __syncthreads();

  // ---- Prologue: build both K slabs (32x1024 fp16 each) via MFMA ----
  const int m = lane & 15, q = lane >> 4;
  const int g = lane >> 3, sub = lane & 7;
  const int sw2 = wave & 1, q4 = wave >> 1;  // row-tile (2), col-quarter (4)
  h8 kaA[4], kbA[4], kaB[4], kbB[4];
#pragma unroll
  for (int sl = 0; sl < 2; sl++) {
    int b = sl ? bB : bA;
    short8v a0 = *(const short8v*)&xs[(sl * 32 + sw2 * 16 + m) * LSTRIDE + q * 8];
    short8v a1 = *(const short8v*)&xs[(sl * 32 + sw2 * 16 + m) * LSTRIDE + 32 + q * 8];
    float xa[4];
#pragma unroll
    for (int reg = 0; reg < 4; reg++)
      xa[reg] = x2L[sl * 32 + sw2 * 16 + q * 4 + reg];
#pragma unroll
    for (int k = 0; k < 8; k++) {
      {  // stage 128 y rows of batch b
        int idx = t;
#pragma unroll
        for (int rep = 0; rep < 2; rep++, idx += 512) {
          int r = idx >> 3, c = idx & 7;
          *(short8v*)&ys[r >> 6][(r & 63) * LSTRIDE + c * 8] = *(const short8v*)(
              (const short*)syh + ((size_t)b * NPTS + 128 * k + r) * DIM + c * 8);
        }
      }
      __syncthreads();
#pragma unroll
      for (int tjq = 0; tjq < 2; tjq++) {
        int jcol = q4 * 32 + tjq * 16 + m;  // 0..127 within k-step
        short8v b0 = *(const short8v*)&ys[jcol >> 6][(jcol & 63) * LSTRIDE + q * 8];
        short8v b1 = *(const short8v*)&ys[jcol >> 6][(jcol & 63) * LSTRIDE + 32 + q * 8];
        float4v c = {0.f, 0.f, 0.f, 0.f};
        c = __builtin_amdgcn_mfma_f32_16x16x32_bf16(a0, b0, c, 0, 0, 0);
        c = __builtin_amdgcn_mfma_f32_16x16x32_bf16(a1, b1, c, 0, 0, 0);
        float y2v = y2[(size_t)b * NPTS + 128 * k + jcol];
#pragma unroll
        for (int reg = 0; reg < 4; reg++) {
          float C = xa[reg] + y2v - 2.0f * c[reg];
          _Float16 kv = (_Float16)__expf(-INV_EPS * C);
          os[jcol >> 6][(sw2 * 16 + q * 4 + reg) * LSTRIDE + (jcol & 63)] =
              *(const short*)&kv;
        }
      }
      __syncthreads();
      {
        int e0 = (2 * k) & 7, e1 = (2 * k + 1) & 7;
        if (g == e0 || g == e1) {
          const short* srcp = (g == e0) ? &os[0][0] : &os[1][0];
#pragma unroll
          for (int rr = 0; rr < 4; rr++) {
            h8 v = *(const h8*)&srcp[(wave * 4 + rr) * LSTRIDE + sub * 8];
            if (sl == 0) {
              if (k < 4) kaA[rr] = v; else kbA[rr] = v;
            } else {
              if (k < 4) kaB[rr] = v; else kbB[rr] = v;
            }
          }
        }
      }
      __syncthreads();
    }
  }

  for (int j = t; j < NPTS; j += 512) {
    wLA[j] = 1.f; wLB[j] = 1.f;
    whA[j] = (_Float16)1.f; whB[j] = (_Float16)1.f;
  }
  __syncthreads();

  float euA[4], euB[4], epA[4], epB[4];  // eu = exp(u/eps)
#pragma unroll
  for (int r = 0; r < 4; r++) { euA[r] = 1.f; euB[r] = 1.f; }
  int it = 0;
  const int j0 = (t + s * 32) & 1023, j1 = j0 ^ 512;  // staggered atomics

  while (true) {
#pragma unroll
    for (int r = 0; r < 4; r++) { epA[r] = euA[r]; epB[r] = euB[r]; }
    // ---- Phase A (slab A) ----
    PHASEA(whA, kaA, kbA, euA, cpA, derrA)
    __syncthreads();  // S1: cpA visible
    {
      float* cs = colsum + ((size_t)(it % 3) * BATCH + bA) * NPTS;
      float s0 = 0.f, s1 = 0.f;
#pragma unroll
      for (int w = 0; w < 8; w++) { s0 += cpA[w][j0]; s1 += cpA[w][j1]; }
      unsafeAtomicAdd(&cs[j0], s0);
      unsafeAtomicAdd(&cs[j1], s1);
    }
    // ---- Phase A (slab B): A-atomics ack in flight underneath ----
    PHASEA(whB, kaB, kbB, euB, cpB, derrB)
    if (it >= 1 && t < BATCH) {  // lag-1 errB retrieval overlaps too
      float v;
      while ((v = ATOMIC_LD(&errB[(it - 1) * BATCH + t])) < 0.f) {}
      errbL[t] = v;
    }
    __syncthreads();  // S2: A atomics drained + cpB/errbL visible
    if (t == 0) {
      float e = 0.f;
#pragma unroll
      for (int w = 0; w < 8; w++) e += derrA[w];
      ATOMIC_ST(&fA[bA * 32 + s], packTag(it + 2, e));
    }
    {
      float* cs = colsum + ((size_t)(it % 3) * BATCH + bB) * NPTS;
      float s0 = 0.f, s1 = 0.f;
#pragma unroll
      for (int w = 0; w < 8; w++) { s0 += cpB[w][j0]; s1 += cpB[w][j1]; }
      unsafeAtomicAdd(&cs[j0], s0);
      unsafeAtomicAdd(&cs[j1], s1);
    }
    // ---- lag-1 global stop (uniform across all blocks) ----
    if (it >= 1) {
      float errv = 0.f;
#pragma unroll
      for (int k = 0; k < BATCH; k++) errv += errbL[k];
      if (errv * (1.0f / (float)BATCH) < THRESHF) {
        // reference stopped after body it-1: undo this iteration's u update
#pragma unroll
        for (int r = 0; r < 4; r++) { euA[r] = epA[r]; euB[r] = epB[r]; }
        break;
      }
    }
    // ---- poll A (B-atomics ack in flight under the spin) ----
    float dpA = 0.f;
    if (t < 32)
      dpA = __uint_as_float((unsigned)pollTag(&fA[bA * 32 + t], it + 2));
    __syncthreads();  // S3: pollA joined + B atomics drained
    if (t == 0) {
      float e = 0.f;
#pragma unroll
      for (int w = 0; w < 8; w++) e += derrB[w];
      ATOMIC_ST(&fB[bA * 32 + s], packTag(it + 2, e));
    }
    // csA loads issued now; values final per fA tags
    const float* csA = colsum + ((size_t)(it % 3) * BATCH + bA) * NPTS;
    float a0v = ATOMIC_LD((float*)&csA[t]);
    float a1v = ATOMIC_LD((float*)&csA[t + 512]);
    // zero bA's it+2 buffer (safe: all bA writers flagged it+2)
    if (t < 32)
      ATOMIC_ST(&colsum[((size_t)((it + 2) % 3) * BATCH + bA) * NPTS + s * 32 + t],
                0.f);
    // ---- poll B (csA flight hides under the spin) ----
    float dpB = 0.f;
    if (t < 32)
      dpB = __uint_as_float((unsigned)pollTag(&fB[bA * 32 + t], it + 2));
    if (wave == 0 && s == 0) {  // leader publishes errB for batch bA
      float e = (lane < 32) ? dpA : 0.f;
#pragma unroll
      for (int off = 16; off; off >>= 1) e += __shfl_xor(e, off, 32);
      if (lane == 0) ATOMIC_ST(&errB[it * BATCH + bA], e);
    }
    __syncthreads();  // S5: pollB joined
    const float* csB = colsum + ((size_t)(it % 3) * BATCH + bB) * NPTS;
    float b0v = ATOMIC_LD((float*)&csB[t]);
    float b1v = ATOMIC_LD((float*)&csB[t + 512]);
    if (t < 32)
      ATOMIC_ST(&colsum[((size_t)((it + 2) % 3) * BATCH + bB) * NPTS + s * 32 + t],
                0.f);
    // ---- Phase B (A): x1024 fold is bit-exact (see round-5 comment) ----
    {
      float w0 = wLA[t];
      float wn0 = mu_c * w0 *
                  __builtin_amdgcn_rcpf(w0 * a0v + (1e-6f * 1024.0f)) * 1024.0f;
      wLA[t] = wn0; whA[t] = (_Float16)wn0;
      float w1 = wLA[t + 512];
      float wn1 = mu_c * w1 *
                  __builtin_amdgcn_rcpf(w1 * a1v + (1e-6f * 1024.0f)) * 1024.0f;
      wLA[t + 512] = wn1; whA[t + 512] = (_Float16)wn1;
    }
    if (wave == 0 && s == 0) {  // leader publishes errB for batch bB
      float e = (lane < 32) ? dpB : 0.f;
#pragma unroll
      for (int off = 16; off; off >>= 1) e += __shfl_xor(e, off, 32);
      if (lane == 0) ATOMIC_ST(&errB[it * BATCH + bB], e);
    }
    // ---- Phase B (B): csB flight hidden under Phase B (A) ----
    {
      float w0 = wLB[t];
      float wn0 = mu_c * w0 *
                  __builtin_amdgcn_rcpf(w0 * b0v + (1e-6f * 1024.0f)) * 1024.0f;
      wLB[t] = wn0; whB[t] = (_Float16)wn0;
      float w1 = wLB[t + 512];
      float wn1 = mu_c * w1 *
                  __builtin_amdgcn_rcpf(w1 * b1v + (1e-6f * 1024.0f)) * 1024.0f;
      wLB[t + 512] = wn1; whB[t + 512] = (_Float16)wn1;
    }
    it++;
    if (it >= MAX_ITER) break;
    __syncthreads();  // S6: w/wh visible before next Phase A
  }

  // ---- Final cost: pi = a_i*K*w_j, C = -eps*log(K), both slabs ----
  {
    __syncthreads();
    float csum = 0.f;
    {
      const float4* w4 = (const float4*)wLA;
      float wreg[16];
      *(float4*)&wreg[0] = w4[2 * lane];
      *(float4*)&wreg[4] = w4[2 * lane + 1];
      *(float4*)&wreg[8] = w4[128 + 2 * lane];
      *(float4*)&wreg[12] = w4[128 + 2 * lane + 1];
#pragma unroll
      for (int rr = 0; rr < 4; rr++) {
        float ai = euA[rr];
#pragma unroll
        for (int n = 0; n < 8; n++) {
          float kf = (float)kaA[rr][n];
          if (kf > 0.f) csum += ai * wreg[n] * kf * (-EPSF * __logf(kf));
          float kg = (float)kbA[rr][n];
          if (kg > 0.f) csum += ai * wreg[8 + n] * kg * (-EPSF * __logf(kg));
        }
      }
    }
    {
      const float4* w4 = (const float4*)wLB;
      float wreg[16];
      *(float4*)&wreg[0] = w4[2 * lane];
      *(float4*)&wreg[4] = w4[2 * lane + 1];
      *(float4*)&wreg[8] = w4[128 + 2 * lane];
      *(float4*)&wreg[12] = w4[128 + 2 * lane + 1];
#pragma unroll
      for (int rr = 0; rr < 4; rr++) {
        float ai = euB[rr];
#pragma unroll
        for (int n = 0; n < 8; n++) {
          float kf = (float)kaB[rr][n];
          if (kf > 0.f) csum += ai * wreg[n] * kf * (-EPSF * __logf(kf));
          float kg = (float)kbB[rr][n];
          if (kg > 0.f) csum += ai * wreg[8 + n] * kg * (-EPSF * __logf(kg));
        }
      }
    }
    csum = waveSum(csum);
    if (lane == 0) derrA[wave] = csum;
    __syncthreads();
    if (t == 0) {
      float cst = 0.f;
#pragma unroll
      for (int w = 0; w < 8; w++) cst += derrA[w];
      ATOMIC_ST(&costPart[blk], cst + 1.0f);  // bias: sentinel-safe vs poison
    }
    // block 0 gathers all 256 partials and writes the scalar output
    if (blk == 0) {
      if (t < 256) {
        float v;
        while ((v = ATOMIC_LD(&costPart[t])) < 0.5f) {}
        cpA[0][t] = v;
      }
      __syncthreads();
      if (wave == 0) {
        float gv = cpA[0][lane] + cpA[0][lane + 64] + cpA[0][lane + 128] +
                   cpA[0][lane + 192];
        gv = waveSum(gv);
        if (lane == 0) out[0] = (gv - 256.0f) * (1.0f / (float)BATCH);
      }
    }
  }
}

extern "C" void kernel_launch(void* const* d_in, const int* in_sizes, int n_in,
                              void* d_out, int out_size, void* d_ws,
                              size_t ws_size, hipStream_t stream) {
  (void)in_sizes; (void)n_in; (void)out_size; (void)ws_size;
  const float* x = (const float*)d_in[0];
  const float* y = (const float*)d_in[1];
  float* out = (float*)d_out;

  char* ws = (char*)d_ws;
  size_t off = 0;
  auto alloc = [&](size_t nbytes) -> void* {
    void* p = (void*)(ws + off);
    off = (off + nbytes + 255) & ~(size_t)255;
    return p;
  };
  __hip_bfloat16* syh = (__hip_bfloat16*)alloc((size_t)BATCH * NPTS * DIM * 2);
  float* y2 = (float*)alloc((size_t)BATCH * NPTS * 4);
  float* colsum = (float*)alloc((size_t)3 * BATCH * NPTS * 4);
  long long* fA = (long long*)alloc((size_t)8 * 32 * 8);
  long long* fB = (long long*)alloc((size_t)8 * 32 * 8);
  float* errB = (float*)alloc((size_t)MAX_ITER * BATCH * 4);
  float* costPart = (float*)alloc(256 * 4);

  void* args[] = {&x, &y, &syh, &y2, &colsum, &fA, &fB,
                  &errB, &costPart, &out};
  hipLaunchCooperativeKernel((void*)sinkhorn_fused, dim3(256), dim3(512), args,
                             0, stream);
}